// Round 1
// baseline (533.915 us; speedup 1.0000x reference)
//
#include <hip/hip_runtime.h>

// ---------------------------------------------------------------------------
// Attention_msa: B=1, N=2048, C=1024, H=8, d=128, SCALE=25, SIM_THRESH=0.75
// ---------------------------------------------------------------------------

#define NTOK 2048
#define CDIM 1024
#define OD   5120   // 3C (cls: q,k,v) + 2C (reg: q,k)

typedef __attribute__((ext_vector_type(8))) short bf16x8;
typedef __attribute__((ext_vector_type(4))) short s16x4;
typedef __attribute__((ext_vector_type(2))) short s16x2;
typedef __attribute__((ext_vector_type(4))) float f32x4;

#define MFMA16(a,b,c) __builtin_amdgcn_mfma_f32_16x16x32_bf16((a),(b),(c),0,0,0)

__device__ __forceinline__ short f2bf(float x){
  unsigned u = __float_as_uint(x);
  u += 0x7FFFu + ((u >> 16) & 1u);           // round-to-nearest-even
  return (short)(u >> 16);
}

// ---------------------------------------------------------------------------
// Kernel 1: QKV GEMM.  tmp[m][o] = X[m][:] . W[o][:],  o in [0,5120)
//   o <  3072 : X = x_cls, W = W_qkv_cls rows o
//   o >= 3072 : X = x_reg, W = W_qkv_reg rows o-3072   (v_reg never computed)
// 64x64 block tile, 4 waves (2x2), 16x16x32 bf16 MFMA, BK=32.
// ---------------------------------------------------------------------------
__global__ __launch_bounds__(256,2) void k_qkv(
    const float* __restrict__ xcls, const float* __restrict__ xreg,
    const float* __restrict__ Wcls, const float* __restrict__ Wreg,
    float* __restrict__ tmp)
{
  const int m0 = blockIdx.x * 64;
  const int o0 = blockIdx.y * 64;
  const float* X; const float* W; int wrow;
  if (o0 < 3072){ X = xcls; W = Wcls; wrow = o0; }
  else          { X = xreg; W = Wreg; wrow = o0 - 3072; }

  __shared__ short As[64][40];   // pad to 40 (80B rows, 16B aligned)
  __shared__ short Bs[64][40];

  const int tid  = threadIdx.x;
  const int lane = tid & 63;
  const int wid  = tid >> 6;
  const int wm   = (wid >> 1) * 32;
  const int wo   = (wid & 1) * 32;
  const int fr   = lane & 15;
  const int fk   = (lane >> 4) * 8;

  f32x4 acc[2][2] = {};

  for (int k0 = 0; k0 < CDIM; k0 += 32){
    #pragma unroll
    for (int it = 0; it < 2; ++it){
      int idx = tid + it*256;          // 0..511
      int r = idx >> 3;                // 64 rows
      int c = (idx & 7) << 2;          // 8 float4 per 32-col row
      float4 xv = *(const float4*)(X + (size_t)(m0+r)*CDIM + k0 + c);
      *(s16x4*)&As[r][c] = (s16x4){ f2bf(xv.x), f2bf(xv.y), f2bf(xv.z), f2bf(xv.w) };
      float4 wv = *(const float4*)(W + (size_t)(wrow+r)*CDIM + k0 + c);
      *(s16x4*)&Bs[r][c] = (s16x4){ f2bf(wv.x), f2bf(wv.y), f2bf(wv.z), f2bf(wv.w) };
    }
    __syncthreads();
    bf16x8 a0 = *(const bf16x8*)&As[wm      + fr][fk];
    bf16x8 a1 = *(const bf16x8*)&As[wm + 16 + fr][fk];
    bf16x8 b0 = *(const bf16x8*)&Bs[wo      + fr][fk];
    bf16x8 b1 = *(const bf16x8*)&Bs[wo + 16 + fr][fk];
    acc[0][0] = MFMA16(a0,b0,acc[0][0]);
    acc[0][1] = MFMA16(a0,b1,acc[0][1]);
    acc[1][0] = MFMA16(a1,b0,acc[1][0]);
    acc[1][1] = MFMA16(a1,b1,acc[1][1]);
    __syncthreads();
  }
  #pragma unroll
  for (int fi=0;fi<2;fi++)
    #pragma unroll
    for (int fj=0;fj<2;fj++)
      #pragma unroll
      for (int r=0;r<4;r++){
        int mm = m0 + wm + fi*16 + (lane>>4)*4 + r;    // C row = (lane>>4)*4+reg
        int oo = o0 + wo + fj*16 + fr;                 // C col = lane&15
        tmp[(size_t)mm*OD + oo] = acc[fi][fj][r];
      }
}

// ---------------------------------------------------------------------------
// Kernel 2: per-(n,chunk,head) L2 norm + scatter to bf16 buffers.
// chunk: 0=q_cls 1=k_cls 2=v_cls 3=q_reg 4=k_reg ; col base = chunk*1024+h*128
// v chunk additionally writes raw bf16 (vb), and raw f32 -> x_ori half of out.
// ---------------------------------------------------------------------------
__global__ __launch_bounds__(256,4) void k_norm(
    const float* __restrict__ tmp, float* __restrict__ out,
    short* __restrict__ qc, short* __restrict__ kc,
    short* __restrict__ qr, short* __restrict__ kr,
    short* __restrict__ vn, short* __restrict__ vb)
{
  int task = blockIdx.x*4 + (threadIdx.x>>6);   // 81920 tasks
  int lane = threadIdx.x & 63;
  int n = task / 40;
  int rem = task - n*40;
  int chunk = rem >> 3;
  int h = rem & 7;
  const float* src = tmp + (size_t)n*OD + (chunk<<10) + h*128;
  float2 v = *(const float2*)(src + lane*2);
  float ss = v.x*v.x + v.y*v.y;
  #pragma unroll
  for (int m=1;m<64;m<<=1) ss += __shfl_xor(ss, m);
  float rn = 1.0f / sqrtf(ss);
  size_t base = ((size_t)h*NTOK + n)*128 + lane*2;
  s16x2 nv = { f2bf(v.x*rn), f2bf(v.y*rn) };
  switch(chunk){
    case 0: *(s16x2*)&qc[base] = nv; break;
    case 1: *(s16x2*)&kc[base] = nv; break;
    case 3: *(s16x2*)&qr[base] = nv; break;
    case 4: *(s16x2*)&kr[base] = nv; break;
    default: {
      *(s16x2*)&vn[base] = nv;
      *(s16x2*)&vb[base] = (s16x2){ f2bf(v.x), f2bf(v.y) };
      *(float2*)&out[(size_t)n*2048 + 1024 + h*128 + lane*2] = v;  // x_ori (raw f32)
      break;
    }
  }
}

// ---------------------------------------------------------------------------
// Kernel 3: transpose raw v (bf16) [h][n][d] -> vT [h][d][n]  (PV B-operand)
// ---------------------------------------------------------------------------
__global__ __launch_bounds__(256,4) void k_vT(
    const short* __restrict__ vb, short* __restrict__ vT)
{
  int b = blockIdx.x;              // 8*32*2 = 512
  int h  = b >> 6;
  int nt = (b >> 1) & 31;
  int dt = b & 1;
  __shared__ short t[64][72];
  int tid = threadIdx.x;
  int r  = tid >> 2;
  int c0 = (tid & 3) << 4;
  #pragma unroll
  for (int u=0;u<2;u++){
    bf16x8 val = *(const bf16x8*)&vb[((size_t)h*NTOK + nt*64 + r)*128 + dt*64 + c0 + u*8];
    #pragma unroll
    for (int e=0;e<8;e++) t[r][c0+u*8+e] = val[e];
  }
  __syncthreads();
  #pragma unroll
  for (int u=0;u<2;u++){
    bf16x8 o;
    #pragma unroll
    for (int e=0;e<8;e++) o[e] = t[c0+u*8+e][r];
    *(bf16x8*)&vT[((size_t)h*128 + dt*64 + r)*NTOK + nt*64 + c0 + u*8] = o;
  }
}

// ---------------------------------------------------------------------------
// Kernel 4: attention pass 1 (per head, per 16-row wave tile):
//   stream j in steps of 32; S = q.k^T (MFMA); e = mask ? exp(S*25*score_j) : 1
//   row-sums (f32) and U = E @ V (MFMA, E via wave-local LDS relayout).
//   Writes row sums s_cls/s_reg and x half of out = 0.5*(Uc/sc + Ur/sr).
// ---------------------------------------------------------------------------
__global__ __launch_bounds__(256,1) void k_attn(
    const short* __restrict__ qc, const short* __restrict__ kc,
    const short* __restrict__ qr, const short* __restrict__ kr,
    const short* __restrict__ vT,
    const float* __restrict__ csc, const float* __restrict__ fsc,
    float* __restrict__ s_cls, float* __restrict__ s_reg,
    float* __restrict__ out)
{
  const int h    = blockIdx.y;
  const int wid  = threadIdx.x >> 6;
  const int lane = threadIdx.x & 63;
  const int i0   = blockIdx.x*64 + wid*16;
  const int fr   = lane & 15;
  const int fk   = (lane >> 4) * 8;
  const size_t hN = (size_t)h * NTOK;

  __shared__ short Et[4][2][16][32];
  short (*Ec)[32] = Et[wid][0];
  short (*Er)[32] = Et[wid][1];

  bf16x8 aq[4], ar[4];
  #pragma unroll
  for (int kk=0;kk<4;kk++){
    aq[kk] = *(const bf16x8*)&qc[(hN + i0 + fr)*128 + kk*32 + fk];
    ar[kk] = *(const bf16x8*)&qr[(hN + i0 + fr)*128 + kk*32 + fk];
  }
  const int rowbase = i0 + ((lane>>4)<<2);
  float sci[4], sfi[4];
  #pragma unroll
  for (int r=0;r<4;r++){ sci[r]=csc[rowbase+r]; sfi[r]=fsc[rowbase+r]; }

  f32x4 Uc[8] = {}; f32x4 Ur[8] = {};
  float pc[4] = {0,0,0,0}, pr[4] = {0,0,0,0};

  for (int j0 = 0; j0 < NTOK; j0 += 32){
    f32x4 Sc[2] = {}; f32x4 Sr[2] = {};
    #pragma unroll
    for (int f=0; f<2; f++){
      #pragma unroll
      for (int kk=0;kk<4;kk++){
        bf16x8 b  = *(const bf16x8*)&kc[(hN + j0 + f*16 + fr)*128 + kk*32 + fk];
        Sc[f] = MFMA16(aq[kk], b, Sc[f]);
        bf16x8 b2 = *(const bf16x8*)&kr[(hN + j0 + f*16 + fr)*128 + kk*32 + fk];
        Sr[f] = MFMA16(ar[kk], b2, Sr[f]);
      }
    }
    #pragma unroll
    for (int f=0; f<2; f++){
      int col = j0 + f*16 + fr;
      float sjc = csc[col], sjf = fsc[col];
      #pragma unroll
      for (int r=0;r<4;r++){
        float ec = (sjc > sci[r]-0.1f) ? __expf(Sc[f][r]*(25.0f*sjc)) : 1.0f;
        float er = (sjf > sfi[r]-0.1f) ? __expf(Sr[f][r]*(25.0f*sjf)) : 1.0f;
        pc[r] += ec; pr[r] += er;
        Ec[(lane>>4)*4+r][f*16+fr] = f2bf(ec);
        Er[(lane>>4)*4+r][f*16+fr] = f2bf(er);
      }
    }
    // wave-local LDS relayout: E rows (i) x 32 (j) -> A-fragment
    bf16x8 ea = *(const bf16x8*)&Ec[fr][fk];
    bf16x8 eb = *(const bf16x8*)&Er[fr][fk];
    #pragma unroll
    for (int c=0;c<8;c++){
      bf16x8 bv = *(const bf16x8*)&vT[((size_t)h*128 + c*16 + fr)*NTOK + j0 + fk];
      Uc[c] = MFMA16(ea, bv, Uc[c]);
      Ur[c] = MFMA16(eb, bv, Ur[c]);
    }
  }
  // row sums: butterfly over lane bits 0..3 (16 lanes share the 4 rows)
  #pragma unroll
  for (int m=1;m<16;m<<=1){
    #pragma unroll
    for (int r=0;r<4;r++){ pc[r]+=__shfl_xor(pc[r],m); pr[r]+=__shfl_xor(pr[r],m); }
  }
  if (fr == 0){
    #pragma unroll
    for (int r=0;r<4;r++){ s_cls[hN+rowbase+r]=pc[r]; s_reg[hN+rowbase+r]=pr[r]; }
  }
  float ipc[4], ipr[4];
  #pragma unroll
  for (int r=0;r<4;r++){ ipc[r]=1.0f/pc[r]; ipr[r]=1.0f/pr[r]; }
  #pragma unroll
  for (int c=0;c<8;c++)
    #pragma unroll
    for (int r=0;r<4;r++){
      float val = 0.5f*(Uc[c][r]*ipc[r] + Ur[c][r]*ipr[r]);
      out[(size_t)(rowbase+r)*2048 + h*128 + c*16 + fr] = val;
    }
}

// ---------------------------------------------------------------------------
// Kernel 5: sim_attn (head-mean attention) + similarity mask.
// Wave tile 16(i) x 64(j); loop h inside; raw = Vn.Vn^T accumulated over h.
// Writes sim into out[4M + i*2048+j], mask byte = (raw > 6.0).
// ---------------------------------------------------------------------------
__global__ __launch_bounds__(256,2) void k_sim(
    const short* __restrict__ qc, const short* __restrict__ kc,
    const short* __restrict__ qr, const short* __restrict__ kr,
    const short* __restrict__ vn,
    const float* __restrict__ csc, const float* __restrict__ fsc,
    const float* __restrict__ s_cls, const float* __restrict__ s_reg,
    unsigned char* __restrict__ mask, float* __restrict__ out)
{
  const int wid  = threadIdx.x >> 6;
  const int lane = threadIdx.x & 63;
  const int tile = blockIdx.x*4 + wid;     // 4096 tiles: 128 i-tiles x 32 j-tiles
  const int i0 = (tile >> 5) * 16;
  const int j0 = (tile & 31) * 64;
  const int fr = lane & 15;
  const int fk = (lane >> 4) * 8;
  const int row = i0 + ((lane>>4)<<2);

  f32x4 sim[4] = {}; f32x4 raw[4] = {};
  float sci[4], sfi[4];
  #pragma unroll
  for (int r=0;r<4;r++){ sci[r]=csc[row+r]; sfi[r]=fsc[row+r]; }
  float sjc[4], sjf[4];
  #pragma unroll
  for (int js=0;js<4;js++){ sjc[js]=csc[j0+js*16+fr]; sjf[js]=fsc[j0+js*16+fr]; }

  for (int h=0; h<8; h++){
    const size_t hb = (size_t)h * NTOK;
    bf16x8 aq[4], ar[4], av[4];
    #pragma unroll
    for (int kk=0;kk<4;kk++){
      aq[kk] = *(const bf16x8*)&qc[(hb + i0 + fr)*128 + kk*32 + fk];
      ar[kk] = *(const bf16x8*)&qr[(hb + i0 + fr)*128 + kk*32 + fk];
      av[kk] = *(const bf16x8*)&vn[(hb + i0 + fr)*128 + kk*32 + fk];
    }
    float iscl[4], isrl[4];
    #pragma unroll
    for (int r=0;r<4;r++){ iscl[r]=1.0f/s_cls[hb+row+r]; isrl[r]=1.0f/s_reg[hb+row+r]; }
    #pragma unroll
    for (int js=0;js<4;js++){
      f32x4 Sc = {}; f32x4 Sr = {};
      #pragma unroll
      for (int kk=0;kk<4;kk++){
        bf16x8 b  = *(const bf16x8*)&kc[(hb + j0+js*16 + fr)*128 + kk*32 + fk];
        Sc = MFMA16(aq[kk], b, Sc);
        bf16x8 b2 = *(const bf16x8*)&kr[(hb + j0+js*16 + fr)*128 + kk*32 + fk];
        Sr = MFMA16(ar[kk], b2, Sr);
        bf16x8 bv = *(const bf16x8*)&vn[(hb + j0+js*16 + fr)*128 + kk*32 + fk];
        raw[js] = MFMA16(av[kk], bv, raw[js]);
      }
      #pragma unroll
      for (int r=0;r<4;r++){
        float ec = (sjc[js] > sci[r]-0.1f) ? __expf(Sc[r]*(25.0f*sjc[js])) : 1.0f;
        float er = (sjf[js] > sfi[r]-0.1f) ? __expf(Sr[r]*(25.0f*sjf[js])) : 1.0f;
        sim[js][r] += ec*iscl[r] + er*isrl[r];
      }
    }
  }
  #pragma unroll
  for (int js=0;js<4;js++)
    #pragma unroll
    for (int r=0;r<4;r++){
      int orow = row + r;
      int ocol = j0 + js*16 + fr;
      out[4194304ull + (size_t)orow*2048 + ocol] = sim[js][r] * (0.5f/8.0f);
      mask[(size_t)orow*2048 + ocol] = raw[js][r] > 6.0f ? 1 : 0;
    }
}

// ---------------------------------------------------------------------------
// Kernel 6: final masked renorm, in place on sim half of out.
//   out = (m * e^s) / sum(m * e^s)   (first-softmax denominator cancels)
// one wave per row.
// ---------------------------------------------------------------------------
__global__ __launch_bounds__(256,4) void k_final(
    float* __restrict__ out, const unsigned char* __restrict__ mask)
{
  int row  = blockIdx.x*4 + (threadIdx.x>>6);
  int lane = threadIdx.x & 63;
  float* sr = out + 4194304ull + (size_t)row*2048;
  const unsigned char* mr = mask + (size_t)row*2048;
  float v[32];
  float sum2 = 0.0f;
  #pragma unroll
  for (int c=0;c<32;c++){
    float e = __expf(sr[c*64 + lane]);
    v[c] = (mr[c*64 + lane] != 0) ? e : 0.0f;
    sum2 += v[c];
  }
  #pragma unroll
  for (int m=1;m<64;m<<=1) sum2 += __shfl_xor(sum2, m);
  float inv = 1.0f / sum2;
  #pragma unroll
  for (int c=0;c<32;c++) sr[c*64 + lane] = v[c]*inv;
}

// ---------------------------------------------------------------------------
extern "C" void kernel_launch(void* const* d_in, const int* in_sizes, int n_in,
                              void* d_out, int out_size, void* d_ws, size_t ws_size,
                              hipStream_t stream)
{
  const float* xcls = (const float*)d_in[0];
  const float* xreg = (const float*)d_in[1];
  const float* csc  = (const float*)d_in[2];
  const float* fsc  = (const float*)d_in[3];
  const float* Wc   = (const float*)d_in[4];
  const float* Wr   = (const float*)d_in[5];
  float* out = (float*)d_out;

  char* ws = (char*)d_ws;
  // region 0: tmp f32 [2048][5120] = 41,943,040 B; after k_norm it is dead and
  // is overlaid by mask (4MB @0) and s_cls/s_reg (@8MB).
  float* tmp          = (float*)ws;
  unsigned char* mask = (unsigned char*)ws;
  float* s_cls        = (float*)(ws + 8u*1024*1024);
  float* s_reg        = (float*)(ws + 8u*1024*1024 + 64*1024);
  short* qc = (short*)(ws + 41943040ull);
  short* kc = qc + 2097152;
  short* qr = kc + 2097152;
  short* kr = qr + 2097152;
  short* vn = kr + 2097152;
  short* vb = vn + 2097152;
  short* vT = vb + 2097152;
  // total ws use: 41,943,040 + 7*4,194,304 = 71,303,168 bytes

  k_qkv  <<<dim3(32,80), 256, 0, stream>>>(xcls, xreg, Wc, Wr, tmp);
  k_norm <<<20480,       256, 0, stream>>>(tmp, out, qc, kc, qr, kr, vn, vb);
  k_vT   <<<512,         256, 0, stream>>>(vb, vT);
  k_attn <<<dim3(32,8),  256, 0, stream>>>(qc, kc, qr, kr, vT, csc, fsc, s_cls, s_reg, out);
  k_sim  <<<1024,        256, 0, stream>>>(qc, kc, qr, kr, vn, csc, fsc, s_cls, s_reg, mask, out);
  k_final<<<512,         256, 0, stream>>>(out, mask);
}